// Round 1
// baseline (386.427 us; speedup 1.0000x reference)
//
#include <hip/hip_runtime.h>
#include <stdint.h>

// ---------------------------------------------------------------------------
// SelfAttentionRope fused pipeline (round 1, correctness-first MFMA version)
//   B=4 T=2048 D=1024 H=16 DH=64   M = B*T = 8192
// Stages:
//   0) rope table [T][32] sin/cos f32
//   1) x f32 -> bf16
//   2) Wqkv, Wproj -> transposed bf16  Wt[N][K]
//   3) gemm<0>: qkv = x@Wqkv + b ; fused RoPE ; scatter Q,K [bh][t][dh] bf16
//      (Q pre-scaled by 1/8) and V transposed [bh][dh][t] bf16
//   4) flash attention (online softmax f32, MFMA bf16) -> attn_out bf16 (B,T,D)
//   5) gemm<1>: out = attn_out@Wproj + b  (f32)
// Workspace: ~93 MB
// ---------------------------------------------------------------------------

typedef float  f32x4 __attribute__((ext_vector_type(4)));
typedef short  s16x8 __attribute__((ext_vector_type(8)));
typedef unsigned short u16;
typedef unsigned int   u32;

#define LOG2E 1.4426950408889634f

__device__ __forceinline__ u16 f2bf(float f) {
  u32 u = __float_as_uint(f);
  u32 r = (u + 0x7fffu + ((u >> 16) & 1u)) >> 16;   // RNE
  return (u16)r;
}

// ---- 0) rope table -------------------------------------------------------
__global__ void rope_table_kernel(float* __restrict__ rsin, float* __restrict__ rcos) {
  int idx = blockIdx.x * 256 + threadIdx.x;   // 2048*32 = 65536
  int t = idx >> 5, i = idx & 31;
  float invf = 1.0f / powf(10000.0f, (float)i * (1.0f / 32.0f));
  float ang = (float)t * invf;
  rsin[idx] = sinf(ang);
  rcos[idx] = cosf(ang);
}

// ---- 1) f32 -> bf16 (8 elems/thread) -------------------------------------
__global__ void cvt_bf16_kernel(const float* __restrict__ in, u16* __restrict__ out) {
  int i = blockIdx.x * 256 + threadIdx.x;
  const float4* p = reinterpret_cast<const float4*>(in) + (size_t)i * 2;
  float4 a = p[0], b = p[1];
  u32 w0 = (u32)f2bf(a.x) | ((u32)f2bf(a.y) << 16);
  u32 w1 = (u32)f2bf(a.z) | ((u32)f2bf(a.w) << 16);
  u32 w2 = (u32)f2bf(b.x) | ((u32)f2bf(b.y) << 16);
  u32 w3 = (u32)f2bf(b.z) | ((u32)f2bf(b.w) << 16);
  reinterpret_cast<uint4*>(out)[i] = make_uint4(w0, w1, w2, w3);
}

// ---- 2) W [K][N] f32 -> Wt [N][K] bf16 (32x32 LDS tile) ------------------
__global__ void transpose_cvt_kernel(const float* __restrict__ W, u16* __restrict__ Wt,
                                     int rows /*K*/, int cols /*N*/) {
  __shared__ float tile[32][33];
  int k0 = blockIdx.y * 32, n0 = blockIdx.x * 32;
  int t = threadIdx.x;
  int c = t & 31, r0 = t >> 5;
  #pragma unroll
  for (int i = 0; i < 4; i++) {
    int r = r0 + i * 8;
    tile[r][c] = W[(size_t)(k0 + r) * cols + n0 + c];
  }
  __syncthreads();
  int kk = t & 31, nn0 = t >> 5;
  #pragma unroll
  for (int i = 0; i < 4; i++) {
    int nn = nn0 + i * 8;
    Wt[(size_t)(n0 + nn) * rows + k0 + kk] = f2bf(tile[kk][nn]);
  }
}

// ---- 3/5) GEMM: A[M][K]bf16 @ Bt[N][K]bf16 ; 128x128 tile, BK=32 ---------
// MODE 0: QKV epilogue (bias + rope + scatter to Q/K/Vt)
// MODE 1: plain f32 out + bias (Cout stride 1024)
template<int MODE>
__global__ __launch_bounds__(256) void gemm_kernel(
    const u16* __restrict__ A, const u16* __restrict__ Bt,
    const float* __restrict__ bias,
    const float* __restrict__ rsin, const float* __restrict__ rcos,
    u16* __restrict__ Qg, u16* __restrict__ Kg, u16* __restrict__ Vtg,
    float* __restrict__ Cout, int K)
{
  __shared__ alignas(16) u16 As[128][40];
  __shared__ alignas(16) u16 Bs[128][40];
  int tid = threadIdx.x;
  int lane = tid & 63, wid = tid >> 6;
  int wr = wid >> 1, wc = wid & 1;
  int l15 = lane & 15, lg = lane >> 4;
  int row0 = blockIdx.x * 128, col0 = blockIdx.y * 128;

  f32x4 acc[4][4] = {};

  int lrow = tid >> 1;
  int lcol = (tid & 1) * 16;

  for (int k0 = 0; k0 < K; k0 += 32) {
    {
      const uint4* ga = reinterpret_cast<const uint4*>(A + (size_t)(row0 + lrow) * K + k0 + lcol);
      uint4 a0 = ga[0], a1 = ga[1];
      const uint4* gb = reinterpret_cast<const uint4*>(Bt + (size_t)(col0 + lrow) * K + k0 + lcol);
      uint4 b0 = gb[0], b1 = gb[1];
      *reinterpret_cast<uint4*>(&As[lrow][lcol])     = a0;
      *reinterpret_cast<uint4*>(&As[lrow][lcol + 8]) = a1;
      *reinterpret_cast<uint4*>(&Bs[lrow][lcol])     = b0;
      *reinterpret_cast<uint4*>(&Bs[lrow][lcol + 8]) = b1;
    }
    __syncthreads();
    s16x8 af[4], bf[4];
    #pragma unroll
    for (int m = 0; m < 4; m++)
      af[m] = *reinterpret_cast<const s16x8*>(&As[wr * 64 + m * 16 + l15][lg * 8]);
    #pragma unroll
    for (int n = 0; n < 4; n++)
      bf[n] = *reinterpret_cast<const s16x8*>(&Bs[wc * 64 + n * 16 + l15][lg * 8]);
    #pragma unroll
    for (int m = 0; m < 4; m++)
      #pragma unroll
      for (int n = 0; n < 4; n++)
        acc[m][n] = __builtin_amdgcn_mfma_f32_16x16x32_bf16(af[m], bf[n], acc[m][n], 0, 0, 0);
    __syncthreads();
  }

  if (MODE == 0) {
    // C row = token (b*2048+t); C col = n in [0,3072): sec 0=Q 1=K 2=V
    int wavecol = col0 + wc * 64;          // multiple of 64 -> one (sec, head)
    int sec = wavecol >> 10;
    int h = (wavecol & 1023) >> 6;
    #pragma unroll
    for (int m = 0; m < 4; m++) {
      int rbase = row0 + wr * 64 + m * 16 + lg * 4;
      if (sec < 2) {
        u16* G = (sec == 0) ? Qg : Kg;
        float qs = (sec == 0) ? 0.125f : 1.0f;   // fold 1/sqrt(dh) into Q
        #pragma unroll
        for (int fc = 0; fc < 2; fc++) {
          int dh = fc * 16 + l15;                // 0..31
          float b1 = bias[wavecol + fc * 16 + l15];
          float b2 = bias[wavecol + fc * 16 + l15 + 32];
          #pragma unroll
          for (int j = 0; j < 4; j++) {
            int grow = rbase + j;
            int bidx = grow >> 11, tt = grow & 2047;
            float sn = rsin[tt * 32 + dh], cs = rcos[tt * 32 + dh];
            float v1 = acc[m][fc][j] + b1;
            float v2 = acc[m][fc + 2][j] + b2;
            float lo = (v1 * cs - v2 * sn) * qs;
            float hi = (v1 * sn + v2 * cs) * qs;
            size_t base = ((size_t)(bidx * 16 + h) * 2048 + tt) * 64;
            G[base + dh]      = f2bf(lo);
            G[base + dh + 32] = f2bf(hi);
          }
        }
      } else {
        #pragma unroll
        for (int fc = 0; fc < 4; fc++) {
          int dh = fc * 16 + l15;
          float bb = bias[wavecol + fc * 16 + l15];
          #pragma unroll
          for (int j = 0; j < 4; j++) {
            int grow = rbase + j;
            int bidx = grow >> 11, tt = grow & 2047;
            Vtg[((size_t)(bidx * 16 + h) * 64 + dh) * 2048 + tt] = f2bf(acc[m][fc][j] + bb);
          }
        }
      }
    }
  } else {
    #pragma unroll
    for (int m = 0; m < 4; m++) {
      int grow = row0 + wr * 64 + m * 16 + lg * 4;
      #pragma unroll
      for (int fc = 0; fc < 4; fc++) {
        int col = col0 + wc * 64 + fc * 16 + l15;
        float bb = bias[col];
        #pragma unroll
        for (int j = 0; j < 4; j++)
          Cout[(size_t)(grow + j) * 1024 + col] = acc[m][fc][j] + bb;
      }
    }
  }
}

// ---- 4) flash attention --------------------------------------------------
// grid: (b*16+h)*32 + qt ; 4 waves x 16 q-rows ; KV tile 64
__global__ __launch_bounds__(256) void attn_kernel(
    const u16* __restrict__ Qg, const u16* __restrict__ Kg, const u16* __restrict__ Vtg,
    u16* __restrict__ Og)
{
  __shared__ alignas(16) u16 Ks[64][72];   // [key][dh]  (padded: 2-way banks)
  __shared__ alignas(16) u16 Vs[64][72];   // [dh][key]
  __shared__ alignas(16) u16 Ps[4][16][72];
  int tid = threadIdx.x, lane = tid & 63, wid = tid >> 6;
  int l15 = lane & 15, lg = lane >> 4;
  int qt = blockIdx.x & 31;
  int bh = blockIdx.x >> 5;                // b*16+h
  int q0 = qt * 64 + wid * 16;

  // Q A-frags (Q already scaled by 1/8)
  s16x8 aq[2];
  #pragma unroll
  for (int kf = 0; kf < 2; kf++)
    aq[kf] = *reinterpret_cast<const s16x8*>(Qg + ((size_t)bh * 2048 + q0 + l15) * 64 + kf * 32 + lg * 8);

  f32x4 o[4] = {};
  const float NEG = -3.0e38f;
  float mrow[4] = {NEG, NEG, NEG, NEG};
  float lrow[4] = {0.f, 0.f, 0.f, 0.f};

  for (int kv = 0; kv < 32; kv++) {
    int t0 = kv * 64;
    #pragma unroll
    for (int c = 0; c < 2; c++) {
      int idx = tid + c * 256;
      int r = idx >> 3, cb = (idx & 7) * 8;
      uint4 kvec = *reinterpret_cast<const uint4*>(Kg + ((size_t)bh * 2048 + t0 + r) * 64 + cb);
      uint4 vvec = *reinterpret_cast<const uint4*>(Vtg + ((size_t)bh * 64 + r) * 2048 + t0 + cb);
      *reinterpret_cast<uint4*>(&Ks[r][cb]) = kvec;
      *reinterpret_cast<uint4*>(&Vs[r][cb]) = vvec;
    }
    __syncthreads();

    // QK^T: S[16 q][64 keys]
    f32x4 s[4];
    #pragma unroll
    for (int nf = 0; nf < 4; nf++) {
      f32x4 z = {0.f, 0.f, 0.f, 0.f};
      s[nf] = z;
      #pragma unroll
      for (int kf = 0; kf < 2; kf++) {
        s16x8 bk = *reinterpret_cast<const s16x8*>(&Ks[nf * 16 + l15][kf * 32 + lg * 8]);
        s[nf] = __builtin_amdgcn_mfma_f32_16x16x32_bf16(aq[kf], bk, s[nf], 0, 0, 0);
      }
    }

    // online softmax (rows r = lg*4+j, keys spread over 16-lane group x 4 frags)
    #pragma unroll
    for (int j = 0; j < 4; j++) {
      float rm = fmaxf(fmaxf(s[0][j], s[1][j]), fmaxf(s[2][j], s[3][j]));
      rm = fmaxf(rm, __shfl_xor(rm, 1));
      rm = fmaxf(rm, __shfl_xor(rm, 2));
      rm = fmaxf(rm, __shfl_xor(rm, 4));
      rm = fmaxf(rm, __shfl_xor(rm, 8));
      float mnew = fmaxf(mrow[j], rm);
      float alpha = exp2f((mrow[j] - mnew) * LOG2E);
      mrow[j] = mnew;
      float rs = 0.f;
      #pragma unroll
      for (int nf = 0; nf < 4; nf++) {
        float p = exp2f((s[nf][j] - mnew) * LOG2E);
        s[nf][j] = p;
        rs += p;
      }
      rs += __shfl_xor(rs, 1);
      rs += __shfl_xor(rs, 2);
      rs += __shfl_xor(rs, 4);
      rs += __shfl_xor(rs, 8);
      lrow[j] = lrow[j] * alpha + rs;
      #pragma unroll
      for (int df = 0; df < 4; df++) o[df][j] *= alpha;
    }

    // P (D-layout) -> LDS -> A-frags
    #pragma unroll
    for (int nf = 0; nf < 4; nf++)
      #pragma unroll
      for (int j = 0; j < 4; j++)
        Ps[wid][lg * 4 + j][nf * 16 + l15] = f2bf(s[nf][j]);

    s16x8 pa[2];
    #pragma unroll
    for (int kf = 0; kf < 2; kf++)
      pa[kf] = *reinterpret_cast<const s16x8*>(&Ps[wid][l15][kf * 32 + lg * 8]);

    #pragma unroll
    for (int df = 0; df < 4; df++)
      #pragma unroll
      for (int kf = 0; kf < 2; kf++) {
        s16x8 bv = *reinterpret_cast<const s16x8*>(&Vs[df * 16 + l15][kf * 32 + lg * 8]);
        o[df] = __builtin_amdgcn_mfma_f32_16x16x32_bf16(pa[kf], bv, o[df], 0, 0, 0);
      }
    __syncthreads();
  }

  // normalize + store attn_out (B,T,D) bf16
  int b = bh >> 4, h = bh & 15;
  #pragma unroll
  for (int j = 0; j < 4; j++) {
    float inv = 1.0f / lrow[j];
    int token = q0 + lg * 4 + j;
    size_t base = ((size_t)b * 2048 + token) * 1024 + h * 64;
    #pragma unroll
    for (int df = 0; df < 4; df++)
      Og[base + df * 16 + l15] = f2bf(o[df][j] * inv);
  }
}

// ---------------------------------------------------------------------------
extern "C" void kernel_launch(void* const* d_in, const int* in_sizes, int n_in,
                              void* d_out, int out_size, void* d_ws, size_t ws_size,
                              hipStream_t stream) {
  const float* x     = (const float*)d_in[0];
  const float* Wqkv  = (const float*)d_in[1];
  const float* bqkv  = (const float*)d_in[2];
  const float* Wproj = (const float*)d_in[3];
  const float* bproj = (const float*)d_in[4];
  float* out = (float*)d_out;

  char* ws = (char*)d_ws;
  size_t off = 0;
  auto alloc = [&](size_t bytes) {
    void* p = ws + off;
    off += (bytes + 255) & ~(size_t)255;
    return p;
  };
  float* rsin  = (float*)alloc((size_t)2048 * 32 * 4);
  float* rcos  = (float*)alloc((size_t)2048 * 32 * 4);
  u16* xb      = (u16*)alloc((size_t)8192 * 1024 * 2);
  u16* Wqkvt   = (u16*)alloc((size_t)3072 * 1024 * 2);
  u16* Wprojt  = (u16*)alloc((size_t)1024 * 1024 * 2);
  u16* Qg      = (u16*)alloc((size_t)64 * 2048 * 64 * 2);
  u16* Kg      = (u16*)alloc((size_t)64 * 2048 * 64 * 2);
  u16* Vtg     = (u16*)alloc((size_t)64 * 2048 * 64 * 2);
  u16* AOg     = (u16*)alloc((size_t)8192 * 1024 * 2);

  rope_table_kernel<<<256, 256, 0, stream>>>(rsin, rcos);
  cvt_bf16_kernel<<<4096, 256, 0, stream>>>(x, xb);
  transpose_cvt_kernel<<<dim3(96, 32), 256, 0, stream>>>(Wqkv, Wqkvt, 1024, 3072);
  transpose_cvt_kernel<<<dim3(32, 32), 256, 0, stream>>>(Wproj, Wprojt, 1024, 1024);
  gemm_kernel<0><<<dim3(64, 24), 256, 0, stream>>>(xb, Wqkvt, bqkv, rsin, rcos,
                                                   Qg, Kg, Vtg, nullptr, 1024);
  attn_kernel<<<2048, 256, 0, stream>>>(Qg, Kg, Vtg, AOg);
  gemm_kernel<1><<<dim3(64, 8), 256, 0, stream>>>(AOg, Wprojt, bproj, nullptr, nullptr,
                                                  nullptr, nullptr, nullptr, out, 1024);
}

// Round 2
// 255.975 us; speedup vs baseline: 1.5096x; 1.5096x over previous
//
#include <hip/hip_runtime.h>
#include <stdint.h>

// ---------------------------------------------------------------------------
// SelfAttentionRope fused pipeline (round 2: m214-style 8-wave 32x32 attention)
//   B=4 T=2048 D=1024 H=16 DH=64   M = B*T = 8192
// ---------------------------------------------------------------------------

typedef float  f32x4  __attribute__((ext_vector_type(4)));
typedef float  f32x16 __attribute__((ext_vector_type(16)));
typedef short  s16x8  __attribute__((ext_vector_type(8)));
typedef unsigned int u32x4 __attribute__((ext_vector_type(4)));
typedef unsigned short u16;
typedef unsigned int   u32;

#define LOG2E 1.4426950408889634f

__device__ __forceinline__ u16 f2bf(float f) {
  u32 u = __float_as_uint(f);
  u32 r = (u + 0x7fffu + ((u >> 16) & 1u)) >> 16;   // RNE
  return (u16)r;
}

__device__ __forceinline__ u32 cvtpk_bf16(float lo, float hi) {
  u32 w;
  asm("v_cvt_pk_bf16_f32 %0, %1, %2" : "=v"(w) : "v"(lo), "v"(hi));
  return w;
}

// ---- 0) rope table -------------------------------------------------------
__global__ void rope_table_kernel(float* __restrict__ rsin, float* __restrict__ rcos) {
  int idx = blockIdx.x * 256 + threadIdx.x;   // 2048*32 = 65536
  int t = idx >> 5, i = idx & 31;
  float invf = 1.0f / powf(10000.0f, (float)i * (1.0f / 32.0f));
  float ang = (float)t * invf;
  rsin[idx] = sinf(ang);
  rcos[idx] = cosf(ang);
}

// ---- 1) f32 -> bf16 (8 elems/thread) -------------------------------------
__global__ void cvt_bf16_kernel(const float* __restrict__ in, u16* __restrict__ out) {
  int i = blockIdx.x * 256 + threadIdx.x;
  const float4* p = reinterpret_cast<const float4*>(in) + (size_t)i * 2;
  float4 a = p[0], b = p[1];
  u32 w0 = (u32)f2bf(a.x) | ((u32)f2bf(a.y) << 16);
  u32 w1 = (u32)f2bf(a.z) | ((u32)f2bf(a.w) << 16);
  u32 w2 = (u32)f2bf(b.x) | ((u32)f2bf(b.y) << 16);
  u32 w3 = (u32)f2bf(b.z) | ((u32)f2bf(b.w) << 16);
  reinterpret_cast<uint4*>(out)[i] = make_uint4(w0, w1, w2, w3);
}

// ---- 2) W [K][N] f32 -> Wt [N][K] bf16 (32x32 LDS tile) ------------------
__global__ void transpose_cvt_kernel(const float* __restrict__ W, u16* __restrict__ Wt,
                                     int rows /*K*/, int cols /*N*/) {
  __shared__ float tile[32][33];
  int k0 = blockIdx.y * 32, n0 = blockIdx.x * 32;
  int t = threadIdx.x;
  int c = t & 31, r0 = t >> 5;
  #pragma unroll
  for (int i = 0; i < 4; i++) {
    int r = r0 + i * 8;
    tile[r][c] = W[(size_t)(k0 + r) * cols + n0 + c];
  }
  __syncthreads();
  int kk = t & 31, nn0 = t >> 5;
  #pragma unroll
  for (int i = 0; i < 4; i++) {
    int nn = nn0 + i * 8;
    Wt[(size_t)(n0 + nn) * rows + k0 + kk] = f2bf(tile[kk][nn]);
  }
}

// ---- 3/5) GEMM: A[M][K]bf16 @ Bt[N][K]bf16 ; 128x128 tile, BK=32 ---------
template<int MODE>
__global__ __launch_bounds__(256) void gemm_kernel(
    const u16* __restrict__ A, const u16* __restrict__ Bt,
    const float* __restrict__ bias,
    const float* __restrict__ rsin, const float* __restrict__ rcos,
    u16* __restrict__ Qg, u16* __restrict__ Kg, u16* __restrict__ Vtg,
    float* __restrict__ Cout, int K)
{
  __shared__ alignas(16) u16 As[128][40];
  __shared__ alignas(16) u16 Bs[128][40];
  int tid = threadIdx.x;
  int lane = tid & 63, wid = tid >> 6;
  int wr = wid >> 1, wc = wid & 1;
  int l15 = lane & 15, lg = lane >> 4;
  int row0 = blockIdx.x * 128, col0 = blockIdx.y * 128;

  f32x4 acc[4][4] = {};

  int lrow = tid >> 1;
  int lcol = (tid & 1) * 16;

  for (int k0 = 0; k0 < K; k0 += 32) {
    {
      const uint4* ga = reinterpret_cast<const uint4*>(A + (size_t)(row0 + lrow) * K + k0 + lcol);
      uint4 a0 = ga[0], a1 = ga[1];
      const uint4* gb = reinterpret_cast<const uint4*>(Bt + (size_t)(col0 + lrow) * K + k0 + lcol);
      uint4 b0 = gb[0], b1 = gb[1];
      *reinterpret_cast<uint4*>(&As[lrow][lcol])     = a0;
      *reinterpret_cast<uint4*>(&As[lrow][lcol + 8]) = a1;
      *reinterpret_cast<uint4*>(&Bs[lrow][lcol])     = b0;
      *reinterpret_cast<uint4*>(&Bs[lrow][lcol + 8]) = b1;
    }
    __syncthreads();
    s16x8 af[4], bf[4];
    #pragma unroll
    for (int m = 0; m < 4; m++)
      af[m] = *reinterpret_cast<const s16x8*>(&As[wr * 64 + m * 16 + l15][lg * 8]);
    #pragma unroll
    for (int n = 0; n < 4; n++)
      bf[n] = *reinterpret_cast<const s16x8*>(&Bs[wc * 64 + n * 16 + l15][lg * 8]);
    #pragma unroll
    for (int m = 0; m < 4; m++)
      #pragma unroll
      for (int n = 0; n < 4; n++)
        acc[m][n] = __builtin_amdgcn_mfma_f32_16x16x32_bf16(af[m], bf[n], acc[m][n], 0, 0, 0);
    __syncthreads();
  }

  if (MODE == 0) {
    int wavecol = col0 + wc * 64;
    int sec = wavecol >> 10;
    int h = (wavecol & 1023) >> 6;
    #pragma unroll
    for (int m = 0; m < 4; m++) {
      int rbase = row0 + wr * 64 + m * 16 + lg * 4;
      if (sec < 2) {
        u16* G = (sec == 0) ? Qg : Kg;
        float qs = (sec == 0) ? 0.125f : 1.0f;
        #pragma unroll
        for (int fc = 0; fc < 2; fc++) {
          int dh = fc * 16 + l15;
          float b1 = bias[wavecol + fc * 16 + l15];
          float b2 = bias[wavecol + fc * 16 + l15 + 32];
          #pragma unroll
          for (int j = 0; j < 4; j++) {
            int grow = rbase + j;
            int bidx = grow >> 11, tt = grow & 2047;
            float sn = rsin[tt * 32 + dh], cs = rcos[tt * 32 + dh];
            float v1 = acc[m][fc][j] + b1;
            float v2 = acc[m][fc + 2][j] + b2;
            float lo = (v1 * cs - v2 * sn) * qs;
            float hi = (v1 * sn + v2 * cs) * qs;
            size_t base = ((size_t)(bidx * 16 + h) * 2048 + tt) * 64;
            G[base + dh]      = f2bf(lo);
            G[base + dh + 32] = f2bf(hi);
          }
        }
      } else {
        #pragma unroll
        for (int fc = 0; fc < 4; fc++) {
          int dh = fc * 16 + l15;
          float bb = bias[wavecol + fc * 16 + l15];
          #pragma unroll
          for (int j = 0; j < 4; j++) {
            int grow = rbase + j;
            int bidx = grow >> 11, tt = grow & 2047;
            Vtg[((size_t)(bidx * 16 + h) * 64 + dh) * 2048 + tt] = f2bf(acc[m][fc][j] + bb);
          }
        }
      }
    }
  } else {
    #pragma unroll
    for (int m = 0; m < 4; m++) {
      int grow = row0 + wr * 64 + m * 16 + lg * 4;
      #pragma unroll
      for (int fc = 0; fc < 4; fc++) {
        int col = col0 + wc * 64 + fc * 16 + l15;
        float bb = bias[col];
        #pragma unroll
        for (int j = 0; j < 4; j++)
          Cout[(size_t)(grow + j) * 1024 + col] = acc[m][fc][j] + bb;
      }
    }
  }
}

// ---- 4) flash attention, 8-wave 32x32 MFMA, swapped-QK in-register softmax
// grid: bx = qt*64 + bh  (same-bh blocks land on one XCD); block 512 threads.
// Per wave: 32 q-rows (q = qt*256 + wid*32 + l31). KV tile = 64, dbuf LDS.
// S^T = mfma(K, Q): lane l31=q holds 32 keys in regs -> in-lane softmax.
// O^T = mfma(V^T, P^T): lane l31=q -> lane-local rescale/normalize.
__global__ __launch_bounds__(512) void attn_kernel(
    const u16* __restrict__ Qg, const u16* __restrict__ Kg, const u16* __restrict__ Vtg,
    u16* __restrict__ Og)
{
  __shared__ alignas(16) u16 Ks[2][4096];   // [key][dh] XOR-swizzled
  __shared__ alignas(16) u16 Vs[2][4096];   // [dh][key] XOR-swizzled
  int tid = threadIdx.x;
  int lane = tid & 63, wid = tid >> 6;
  int l31 = lane & 31, hi = lane >> 5;
  int bh = blockIdx.x & 63, qt = blockIdx.x >> 6;
  int q = qt * 256 + wid * 32 + l31;
  size_t bh2048 = (size_t)bh * 2048;

  // Q B-frags: lane holds Q[q][kc*16 + hi*8 .. +7], kc=0..3 (Q pre-scaled 1/8)
  s16x8 aq[4];
  #pragma unroll
  for (int kc = 0; kc < 4; kc++)
    aq[kc] = *reinterpret_cast<const s16x8*>(Qg + (bh2048 + q) * 64 + kc * 16 + hi * 8);

  f32x16 o0 = {}, o1 = {};
  float m_run = -3.0e38f, l_run = 0.f;

  // staging: thread -> (row = tid>>3, 16B chunk = tid&7); XOR swizzle rows
  int trow = tid >> 3, tc8 = (tid & 7) * 8;
  int swz_st = trow * 64 + (tc8 ^ ((trow & 7) << 3));
  const u16* kg_src = Kg + (bh2048 + trow) * 64 + tc8;
  const u16* vg_src = Vtg + ((size_t)bh * 64 + trow) * 2048 + tc8;

  // prologue: stage tile 0 into buf 0
  {
    uint4 k0v = *reinterpret_cast<const uint4*>(kg_src);
    uint4 v0v = *reinterpret_cast<const uint4*>(vg_src);
    *reinterpret_cast<uint4*>(&Ks[0][swz_st]) = k0v;
    *reinterpret_cast<uint4*>(&Vs[0][swz_st]) = v0v;
  }
  __syncthreads();

  int cur = 0;
  for (int t = 0; t < 32; t++) {
    // issue next-tile global loads early (latency hides under compute)
    uint4 knext, vnext;
    if (t < 31) {
      knext = *reinterpret_cast<const uint4*>(kg_src + (size_t)(t + 1) * 4096);
      vnext = *reinterpret_cast<const uint4*>(vg_src + (t + 1) * 64);
    }

    // ---- QK^T: S^T[key][q], two 32-key chunks ----
    float p[32];
    #pragma unroll
    for (int c = 0; c < 2; c++) {
      f32x16 s = {};
      int key = c * 32 + l31;
      #pragma unroll
      for (int kc = 0; kc < 4; kc++) {
        int col = kc * 16 + hi * 8;
        s16x8 kf = *reinterpret_cast<const s16x8*>(
            &Ks[cur][key * 64 + (col ^ ((key & 7) << 3))]);
        s = __builtin_amdgcn_mfma_f32_32x32x16_bf16(kf, aq[kc], s, 0, 0, 0);
      }
      #pragma unroll
      for (int i = 0; i < 16; i++) p[c * 16 + i] = s[i];
    }

    // ---- in-lane online softmax (lane owns q-row; partner lane = hi^1) ----
    float pm = p[0];
    #pragma unroll
    for (int i = 1; i < 32; i++) pm = fmaxf(pm, p[i]);
    pm = fmaxf(pm, __shfl_xor(pm, 32));
    if (!__all(pm - m_run <= 8.0f)) {          // defer-max (THR=8)
      float mnew = fmaxf(m_run, pm);
      float alpha = exp2f((m_run - mnew) * LOG2E);
      m_run = mnew;
      l_run *= alpha;
      #pragma unroll
      for (int i = 0; i < 16; i++) { o0[i] *= alpha; o1[i] *= alpha; }
    }
    float rs = 0.f;
    #pragma unroll
    for (int i = 0; i < 32; i++) {
      float e = exp2f((p[i] - m_run) * LOG2E);
      p[i] = e; rs += e;
    }
    rs += __shfl_xor(rs, 32);
    l_run += rs;

    // ---- P -> bf16 B-frags via cvt_pk + permlane32_swap ----
    // frag ks covers keys ks*16 + hi*8 + {0..7}; p[reg(+c*16)] holds key
    // (reg&3)+8*(reg>>2)+4*hi  ->  swap exchanges the hi halves.
    u32x4 pw[4];
    #pragma unroll
    for (int ks = 0; ks < 4; ks++) {
      int r0 = ks * 8;
      u32 a0 = cvtpk_bf16(p[r0 + 0], p[r0 + 1]);
      u32 b0 = cvtpk_bf16(p[r0 + 4], p[r0 + 5]);
      u32 a1 = cvtpk_bf16(p[r0 + 2], p[r0 + 3]);
      u32 b1 = cvtpk_bf16(p[r0 + 6], p[r0 + 7]);
      asm volatile("v_permlane32_swap_b32 %0, %1" : "+v"(a0), "+v"(b0));
      asm volatile("v_permlane32_swap_b32 %0, %1" : "+v"(a1), "+v"(b1));
      u32x4 w = {a0, a1, b0, b1};
      pw[ks] = w;
    }

    // ---- PV: O^T[d][q] += V^T-frag x P^T-frag ----
    #pragma unroll
    for (int c2 = 0; c2 < 2; c2++) {
      int d = c2 * 32 + l31;
      #pragma unroll
      for (int ks = 0; ks < 4; ks++) {
        int col = ks * 16 + hi * 8;
        s16x8 vf = *reinterpret_cast<const s16x8*>(
            &Vs[cur][d * 64 + (col ^ ((d & 7) << 3))]);
        s16x8 pf = __builtin_bit_cast(s16x8, pw[ks]);
        if (c2 == 0) o0 = __builtin_amdgcn_mfma_f32_32x32x16_bf16(vf, pf, o0, 0, 0, 0);
        else         o1 = __builtin_amdgcn_mfma_f32_32x32x16_bf16(vf, pf, o1, 0, 0, 0);
      }
    }

    // ---- write next tile into other buffer; single barrier per tile ----
    if (t < 31) {
      *reinterpret_cast<uint4*>(&Ks[cur ^ 1][swz_st]) = knext;
      *reinterpret_cast<uint4*>(&Vs[cur ^ 1][swz_st]) = vnext;
    }
    __syncthreads();
    cur ^= 1;
  }

  // ---- epilogue: normalize (lane-local) and store O^T -> Og[b][t][h*64+d]
  float inv = 1.0f / l_run;
  int b = bh >> 4, h = bh & 15;
  size_t rowbase = ((size_t)b * 2048 + q) * 1024 + h * 64;
  #pragma unroll
  for (int c2 = 0; c2 < 2; c2++) {
    #pragma unroll
    for (int g = 0; g < 4; g++) {
      float e0 = (c2 ? o1[g * 4 + 0] : o0[g * 4 + 0]) * inv;
      float e1 = (c2 ? o1[g * 4 + 1] : o0[g * 4 + 1]) * inv;
      float e2 = (c2 ? o1[g * 4 + 2] : o0[g * 4 + 2]) * inv;
      float e3 = (c2 ? o1[g * 4 + 3] : o0[g * 4 + 3]) * inv;
      u32 w0 = (u32)f2bf(e0) | ((u32)f2bf(e1) << 16);
      u32 w1 = (u32)f2bf(e2) | ((u32)f2bf(e3) << 16);
      int d = c2 * 32 + g * 8 + hi * 4;           // regs g*4..g*4+3 -> d0..d0+3
      uint2 val; val.x = w0; val.y = w1;
      *reinterpret_cast<uint2*>(Og + rowbase + d) = val;
    }
  }
}

// ---------------------------------------------------------------------------
extern "C" void kernel_launch(void* const* d_in, const int* in_sizes, int n_in,
                              void* d_out, int out_size, void* d_ws, size_t ws_size,
                              hipStream_t stream) {
  const float* x     = (const float*)d_in[0];
  const float* Wqkv  = (const float*)d_in[1];
  const float* bqkv  = (const float*)d_in[2];
  const float* Wproj = (const float*)d_in[3];
  const float* bproj = (const float*)d_in[4];
  float* out = (float*)d_out;

  char* ws = (char*)d_ws;
  size_t off = 0;
  auto alloc = [&](size_t bytes) {
    void* p = ws + off;
    off += (bytes + 255) & ~(size_t)255;
    return p;
  };
  float* rsin  = (float*)alloc((size_t)2048 * 32 * 4);
  float* rcos  = (float*)alloc((size_t)2048 * 32 * 4);
  u16* xb      = (u16*)alloc((size_t)8192 * 1024 * 2);
  u16* Wqkvt   = (u16*)alloc((size_t)3072 * 1024 * 2);
  u16* Wprojt  = (u16*)alloc((size_t)1024 * 1024 * 2);
  u16* Qg      = (u16*)alloc((size_t)64 * 2048 * 64 * 2);
  u16* Kg      = (u16*)alloc((size_t)64 * 2048 * 64 * 2);
  u16* Vtg     = (u16*)alloc((size_t)64 * 2048 * 64 * 2);
  u16* AOg     = (u16*)alloc((size_t)8192 * 1024 * 2);

  rope_table_kernel<<<256, 256, 0, stream>>>(rsin, rcos);
  cvt_bf16_kernel<<<4096, 256, 0, stream>>>(x, xb);
  transpose_cvt_kernel<<<dim3(96, 32), 256, 0, stream>>>(Wqkv, Wqkvt, 1024, 3072);
  transpose_cvt_kernel<<<dim3(32, 32), 256, 0, stream>>>(Wproj, Wprojt, 1024, 1024);
  gemm_kernel<0><<<dim3(64, 24), 256, 0, stream>>>(xb, Wqkvt, bqkv, rsin, rcos,
                                                   Qg, Kg, Vtg, nullptr, 1024);
  attn_kernel<<<512, 512, 0, stream>>>(Qg, Kg, Vtg, AOg);
  gemm_kernel<1><<<dim3(64, 8), 256, 0, stream>>>(AOg, Wprojt, bproj, nullptr, nullptr,
                                                  nullptr, nullptr, nullptr, out, 1024);
}

// Round 3
// 223.479 us; speedup vs baseline: 1.7291x; 1.1454x over previous
//
#include <hip/hip_runtime.h>
#include <stdint.h>

// ---------------------------------------------------------------------------
// SelfAttentionRope fused pipeline (round 3)
//   B=4 T=2048 D=1024 H=16 DH=64   M = B*T = 8192
//   - GEMMs: BK=64, XOR-swizzled LDS, global_load_lds(16B), m97 2-barrier loop
//   - attn: static-dbuf unroll x2, in-place log2-domain softmax, gload_lds
// ---------------------------------------------------------------------------

typedef float  f32x4  __attribute__((ext_vector_type(4)));
typedef float  f32x16 __attribute__((ext_vector_type(16)));
typedef short  s16x8  __attribute__((ext_vector_type(8)));
typedef unsigned int u32x4 __attribute__((ext_vector_type(4)));
typedef unsigned short u16;
typedef unsigned int   u32;

#define LOG2E 1.4426950408889634f

__device__ __forceinline__ u16 f2bf(float f) {
  u32 u = __float_as_uint(f);
  u32 r = (u + 0x7fffu + ((u >> 16) & 1u)) >> 16;   // RNE
  return (u16)r;
}

__device__ __forceinline__ u32 cvtpk_bf16(float lo, float hi) {
  u32 w;
  asm("v_cvt_pk_bf16_f32 %0, %1, %2" : "=v"(w) : "v"(lo), "v"(hi));
  return w;
}

// async global -> LDS, 16 B per lane (dest = wave-uniform base + lane*16)
__device__ __forceinline__ void gload_lds16(const u16* g, u16* l) {
  __builtin_amdgcn_global_load_lds(
      (const __attribute__((address_space(1))) uint32_t*)g,
      (__attribute__((address_space(3))) uint32_t*)l, 16, 0, 0);
}

__device__ __forceinline__ float vmax16(f32x16 v) {
  float a = fmaxf(fmaxf(v[0], v[1]), v[2]);
  float b = fmaxf(fmaxf(v[3], v[4]), v[5]);
  float c = fmaxf(fmaxf(v[6], v[7]), v[8]);
  float d = fmaxf(fmaxf(v[9], v[10]), v[11]);
  float e = fmaxf(fmaxf(v[12], v[13]), v[14]);
  float x = fmaxf(fmaxf(a, b), c);
  float y = fmaxf(fmaxf(d, e), v[15]);
  return fmaxf(x, y);
}

// ---- 0) rope table -------------------------------------------------------
__global__ void rope_table_kernel(float* __restrict__ rsin, float* __restrict__ rcos) {
  int idx = blockIdx.x * 256 + threadIdx.x;   // 2048*32 = 65536
  int t = idx >> 5, i = idx & 31;
  float invf = 1.0f / powf(10000.0f, (float)i * (1.0f / 32.0f));
  float ang = (float)t * invf;
  rsin[idx] = sinf(ang);
  rcos[idx] = cosf(ang);
}

// ---- 1) f32 -> bf16 (8 elems/thread) -------------------------------------
__global__ void cvt_bf16_kernel(const float* __restrict__ in, u16* __restrict__ out) {
  int i = blockIdx.x * 256 + threadIdx.x;
  const float4* p = reinterpret_cast<const float4*>(in) + (size_t)i * 2;
  float4 a = p[0], b = p[1];
  u32 w0 = (u32)f2bf(a.x) | ((u32)f2bf(a.y) << 16);
  u32 w1 = (u32)f2bf(a.z) | ((u32)f2bf(a.w) << 16);
  u32 w2 = (u32)f2bf(b.x) | ((u32)f2bf(b.y) << 16);
  u32 w3 = (u32)f2bf(b.z) | ((u32)f2bf(b.w) << 16);
  reinterpret_cast<uint4*>(out)[i] = make_uint4(w0, w1, w2, w3);
}

// ---- 2) W [K][N] f32 -> Wt [N][K] bf16 -----------------------------------
__global__ void transpose_cvt_kernel(const float* __restrict__ W, u16* __restrict__ Wt,
                                     int rows /*K*/, int cols /*N*/) {
  __shared__ float tile[32][33];
  int k0 = blockIdx.y * 32, n0 = blockIdx.x * 32;
  int t = threadIdx.x;
  int c = t & 31, r0 = t >> 5;
  #pragma unroll
  for (int i = 0; i < 4; i++) {
    int r = r0 + i * 8;
    tile[r][c] = W[(size_t)(k0 + r) * cols + n0 + c];
  }
  __syncthreads();
  int kk = t & 31, nn0 = t >> 5;
  #pragma unroll
  for (int i = 0; i < 4; i++) {
    int nn = nn0 + i * 8;
    Wt[(size_t)(n0 + nn) * rows + k0 + kk] = f2bf(tile[kk][nn]);
  }
}

// ---- 3/5) GEMM: A[M][K]bf16 @ Bt[N][K]bf16 ; 128x128 tile, BK=64 ---------
// LDS [128][64] u16, XOR-swizzled at 16B granularity:
//   LDS[row][c8] holds A[row][(c8 ^ (row&7))*8 ..]   (c8 = 16B chunk idx)
// staged via global_load_lds from pre-swizzled global source.
template<int MODE>
__global__ __launch_bounds__(256) void gemm_kernel(
    const u16* __restrict__ A, const u16* __restrict__ Bt,
    const float* __restrict__ bias,
    const float* __restrict__ rsin, const float* __restrict__ rcos,
    u16* __restrict__ Qg, u16* __restrict__ Kg, u16* __restrict__ Vtg,
    float* __restrict__ Cout, int K)
{
  __shared__ alignas(16) u16 As[128][64];
  __shared__ alignas(16) u16 Bs[128][64];
  int tid = threadIdx.x;
  int lane = tid & 63, wid = tid >> 6;
  int wr = wid >> 1, wc = wid & 1;
  int l15 = lane & 15, lg = lane >> 4;
  int row0 = blockIdx.x * 128, col0 = blockIdx.y * 128;

  f32x4 acc[4][4] = {};

  // staging geometry: issue i stages rows wid*32 + i*8 + (lane>>3)
  int sr = lane >> 3, sc = lane & 7;
  int scol = (sc ^ sr) * 8;                       // pre-swizzled source col
  const u16* asrc = A  + (size_t)(row0 + wid * 32 + sr) * K + scol;
  const u16* bsrc = Bt + (size_t)(col0 + wid * 32 + sr) * K + scol;
  u16* aLds = &As[0][0] + wid * 2048;
  u16* bLds = &Bs[0][0] + wid * 2048;

  for (int k0 = 0; k0 < K; k0 += 64) {
    #pragma unroll
    for (int i = 0; i < 4; i++) {
      gload_lds16(asrc + (size_t)(i * 8) * K + k0, aLds + i * 512);
      gload_lds16(bsrc + (size_t)(i * 8) * K + k0, bLds + i * 512);
    }
    __syncthreads();   // drains vmcnt: tiles resident
    #pragma unroll
    for (int kk = 0; kk < 2; kk++) {
      s16x8 af[4], bf[4];
      #pragma unroll
      for (int m = 0; m < 4; m++) {
        int row = wr * 64 + m * 16 + l15;
        int slot = (kk * 4 + lg) ^ (l15 & 7);
        af[m] = *reinterpret_cast<const s16x8*>(&As[row][slot * 8]);
      }
      #pragma unroll
      for (int n = 0; n < 4; n++) {
        int row = wc * 64 + n * 16 + l15;
        int slot = (kk * 4 + lg) ^ (l15 & 7);
        bf[n] = *reinterpret_cast<const s16x8*>(&Bs[row][slot * 8]);
      }
      #pragma unroll
      for (int m = 0; m < 4; m++)
        #pragma unroll
        for (int n = 0; n < 4; n++)
          acc[m][n] = __builtin_amdgcn_mfma_f32_16x16x32_bf16(af[m], bf[n], acc[m][n], 0, 0, 0);
    }
    __syncthreads();   // all reads done before next stage overwrites
  }

  if (MODE == 0) {
    int wavecol = col0 + wc * 64;
    int sec = wavecol >> 10;
    int h = (wavecol & 1023) >> 6;
    #pragma unroll
    for (int m = 0; m < 4; m++) {
      int rbase = row0 + wr * 64 + m * 16 + lg * 4;
      if (sec < 2) {
        u16* G = (sec == 0) ? Qg : Kg;
        // Q gets 1/sqrt(dh) AND log2(e) folded in (softmax done in log2 domain)
        float qs = (sec == 0) ? 0.125f * LOG2E : 1.0f;
        #pragma unroll
        for (int fc = 0; fc < 2; fc++) {
          int dh = fc * 16 + l15;
          float b1 = bias[wavecol + fc * 16 + l15];
          float b2 = bias[wavecol + fc * 16 + l15 + 32];
          #pragma unroll
          for (int j = 0; j < 4; j++) {
            int grow = rbase + j;
            int bidx = grow >> 11, tt = grow & 2047;
            float sn = rsin[tt * 32 + dh], cs = rcos[tt * 32 + dh];
            float v1 = acc[m][fc][j] + b1;
            float v2 = acc[m][fc + 2][j] + b2;
            float lo = (v1 * cs - v2 * sn) * qs;
            float hi = (v1 * sn + v2 * cs) * qs;
            size_t base = ((size_t)(bidx * 16 + h) * 2048 + tt) * 64;
            G[base + dh]      = f2bf(lo);
            G[base + dh + 32] = f2bf(hi);
          }
        }
      } else {
        #pragma unroll
        for (int fc = 0; fc < 4; fc++) {
          int dh = fc * 16 + l15;
          float bb = bias[wavecol + fc * 16 + l15];
          #pragma unroll
          for (int j = 0; j < 4; j++) {
            int grow = rbase + j;
            int bidx = grow >> 11, tt = grow & 2047;
            Vtg[((size_t)(bidx * 16 + h) * 64 + dh) * 2048 + tt] = f2bf(acc[m][fc][j] + bb);
          }
        }
      }
    }
  } else {
    #pragma unroll
    for (int m = 0; m < 4; m++) {
      int grow = row0 + wr * 64 + m * 16 + lg * 4;
      #pragma unroll
      for (int fc = 0; fc < 4; fc++) {
        int col = col0 + wc * 64 + fc * 16 + l15;
        float bb = bias[col];
        #pragma unroll
        for (int j = 0; j < 4; j++)
          Cout[(size_t)(grow + j) * 1024 + col] = acc[m][fc][j] + bb;
      }
    }
  }
}

// ---- 4) flash attention, 8-wave 32x32, static dbuf + gload_lds -----------
// S^T = mfma(K, Q) in log2 domain (Q pre-scaled 0.125*log2e); in-lane softmax.
__global__ __launch_bounds__(512, 4) void attn_kernel(
    const u16* __restrict__ Qg, const u16* __restrict__ Kg, const u16* __restrict__ Vtg,
    u16* __restrict__ Og)
{
  __shared__ alignas(16) u16 Ks[2][4096];   // [key][dh] swizzled (16B chunks)
  __shared__ alignas(16) u16 Vs[2][4096];   // [d][key]  swizzled
  int tid = threadIdx.x;
  int lane = tid & 63, wid = tid >> 6;
  int l31 = lane & 31, hi = lane >> 5;
  int bh = blockIdx.x & 63, qt = blockIdx.x >> 6;
  int q = qt * 256 + wid * 32 + l31;
  size_t bh2048 = (size_t)bh * 2048;

  // Q B-frags
  s16x8 aq[4];
  #pragma unroll
  for (int kc = 0; kc < 4; kc++)
    aq[kc] = *reinterpret_cast<const s16x8*>(Qg + (bh2048 + q) * 64 + kc * 16 + hi * 8);

  f32x16 o0 = {}, o1 = {};
  float m_run = -3.0e38f, l_run = 0.f;

  // staging: wave stages 8 rows (1 KB) of K and of V per tile
  int sr = lane >> 3, sc = lane & 7;
  int scol = (sc ^ sr) * 8;                 // pre-swizzled source col
  const u16* kg_src = Kg + (bh2048 + wid * 8 + sr) * 64 + scol;
  const u16* vg_src = Vtg + ((size_t)bh * 64 + wid * 8 + sr) * 2048 + scol;
  int sdst = wid * 512;

  // loop-invariant LDS read offsets (u16): row (c*32+l31), chunk (j*2+hi)^(l31&7)
  int offs[2][4];
  #pragma unroll
  for (int c = 0; c < 2; c++)
    #pragma unroll
    for (int j = 0; j < 4; j++)
      offs[c][j] = (c * 32 + l31) * 64 + (((j * 2 + hi) ^ (l31 & 7)) * 8);

#define STAGE(TT, BUF) do { \
    gload_lds16(kg_src + (size_t)(TT) * 4096, &Ks[BUF][sdst]); \
    gload_lds16(vg_src + (size_t)(TT) * 64,   &Vs[BUF][sdst]); \
  } while (0)

#define COMPUTE(B) do { \
    const u16* kb = &Ks[B][0]; \
    const u16* vb = &Vs[B][0]; \
    f32x16 s0 = {}, s1 = {}; \
    __builtin_amdgcn_s_setprio(1); \
    _Pragma("unroll") \
    for (int j = 0; j < 4; j++) { \
      s16x8 kf0 = *reinterpret_cast<const s16x8*>(kb + offs[0][j]); \
      s16x8 kf1 = *reinterpret_cast<const s16x8*>(kb + offs[1][j]); \
      s0 = __builtin_amdgcn_mfma_f32_32x32x16_bf16(kf0, aq[j], s0, 0, 0, 0); \
      s1 = __builtin_amdgcn_mfma_f32_32x32x16_bf16(kf1, aq[j], s1, 0, 0, 0); \
    } \
    __builtin_amdgcn_s_setprio(0); \
    float pm = fmaxf(vmax16(s0), vmax16(s1)); \
    pm = fmaxf(pm, __shfl_xor(pm, 32)); \
    if (!__all(pm - m_run <= 11.5f)) {          /* defer-max, log2 units */ \
      float mnew = fmaxf(m_run, pm); \
      float al = exp2f(m_run - mnew); \
      m_run = mnew; l_run *= al; \
      _Pragma("unroll") \
      for (int i = 0; i < 16; i++) { o0[i] *= al; o1[i] *= al; } \
    } \
    float r0 = 0.f, r1 = 0.f, r2 = 0.f, r3 = 0.f; \
    _Pragma("unroll") \
    for (int i = 0; i < 16; i++) { \
      s0[i] = exp2f(s0[i] - m_run); \
      s1[i] = exp2f(s1[i] - m_run); \
    } \
    _Pragma("unroll") \
    for (int i = 0; i < 4; i++) { \
      r0 += s0[i] + s0[i + 8]; \
      r1 += s0[i + 4] + s0[i + 12]; \
      r2 += s1[i] + s1[i + 8]; \
      r3 += s1[i + 4] + s1[i + 12]; \
    } \
    float rs = (r0 + r1) + (r2 + r3); \
    rs += __shfl_xor(rs, 32); \
    l_run += rs; \
    s16x8 pf[4]; \
    _Pragma("unroll") \
    for (int ks = 0; ks < 2; ks++) { \
      int rr = ks * 8; \
      u32 a0 = cvtpk_bf16(s0[rr + 0], s0[rr + 1]); \
      u32 b0 = cvtpk_bf16(s0[rr + 4], s0[rr + 5]); \
      u32 a1 = cvtpk_bf16(s0[rr + 2], s0[rr + 3]); \
      u32 b1 = cvtpk_bf16(s0[rr + 6], s0[rr + 7]); \
      asm volatile("v_permlane32_swap_b32 %0, %1" : "+v"(a0), "+v"(b0)); \
      asm volatile("v_permlane32_swap_b32 %0, %1" : "+v"(a1), "+v"(b1)); \
      u32x4 w = {a0, a1, b0, b1}; \
      pf[ks] = __builtin_bit_cast(s16x8, w); \
    } \
    _Pragma("unroll") \
    for (int ks = 0; ks < 2; ks++) { \
      int rr = ks * 8; \
      u32 a0 = cvtpk_bf16(s1[rr + 0], s1[rr + 1]); \
      u32 b0 = cvtpk_bf16(s1[rr + 4], s1[rr + 5]); \
      u32 a1 = cvtpk_bf16(s1[rr + 2], s1[rr + 3]); \
      u32 b1 = cvtpk_bf16(s1[rr + 6], s1[rr + 7]); \
      asm volatile("v_permlane32_swap_b32 %0, %1" : "+v"(a0), "+v"(b0)); \
      asm volatile("v_permlane32_swap_b32 %0, %1" : "+v"(a1), "+v"(b1)); \
      u32x4 w = {a0, a1, b0, b1}; \
      pf[ks + 2] = __builtin_bit_cast(s16x8, w); \
    } \
    __builtin_amdgcn_s_setprio(1); \
    _Pragma("unroll") \
    for (int ks = 0; ks < 4; ks++) { \
      s16x8 vf = *reinterpret_cast<const s16x8*>(vb + offs[0][ks]); \
      o0 = __builtin_amdgcn_mfma_f32_32x32x16_bf16(vf, pf[ks], o0, 0, 0, 0); \
    } \
    _Pragma("unroll") \
    for (int ks = 0; ks < 4; ks++) { \
      s16x8 vf = *reinterpret_cast<const s16x8*>(vb + offs[1][ks]); \
      o1 = __builtin_amdgcn_mfma_f32_32x32x16_bf16(vf, pf[ks], o1, 0, 0, 0); \
    } \
    __builtin_amdgcn_s_setprio(0); \
  } while (0)

  STAGE(0, 0);
  __syncthreads();

  for (int it = 0; it < 16; it++) {
    STAGE(2 * it + 1, 1);
    COMPUTE(0);
    __syncthreads();          // drains stage->b1; b0 reads complete
    if (it < 15) STAGE(2 * it + 2, 0);
    COMPUTE(1);
    __syncthreads();          // drains stage->b0; b1 reads complete
  }
#undef STAGE
#undef COMPUTE

  // epilogue: normalize (lane-local) and store O^T -> Og[b][t][h*64+d]
  float inv = 1.0f / l_run;
  int b = bh >> 4, h = bh & 15;
  size_t rowbase = ((size_t)b * 2048 + q) * 1024 + h * 64;
  #pragma unroll
  for (int c2 = 0; c2 < 2; c2++) {
    #pragma unroll
    for (int g = 0; g < 4; g++) {
      float e0 = (c2 ? o1[g * 4 + 0] : o0[g * 4 + 0]) * inv;
      float e1 = (c2 ? o1[g * 4 + 1] : o0[g * 4 + 1]) * inv;
      float e2 = (c2 ? o1[g * 4 + 2] : o0[g * 4 + 2]) * inv;
      float e3 = (c2 ? o1[g * 4 + 3] : o0[g * 4 + 3]) * inv;
      u32 w0 = (u32)f2bf(e0) | ((u32)f2bf(e1) << 16);
      u32 w1 = (u32)f2bf(e2) | ((u32)f2bf(e3) << 16);
      int d = c2 * 32 + g * 8 + hi * 4;
      uint2 val; val.x = w0; val.y = w1;
      *reinterpret_cast<uint2*>(Og + rowbase + d) = val;
    }
  }
}

// ---------------------------------------------------------------------------
extern "C" void kernel_launch(void* const* d_in, const int* in_sizes, int n_in,
                              void* d_out, int out_size, void* d_ws, size_t ws_size,
                              hipStream_t stream) {
  const float* x     = (const float*)d_in[0];
  const float* Wqkv  = (const float*)d_in[1];
  const float* bqkv  = (const float*)d_in[2];
  const float* Wproj = (const float*)d_in[3];
  const float* bproj = (const float*)d_in[4];
  float* out = (float*)d_out;

  char* ws = (char*)d_ws;
  size_t off = 0;
  auto alloc = [&](size_t bytes) {
    void* p = ws + off;
    off += (bytes + 255) & ~(size_t)255;
    return p;
  };
  float* rsin  = (float*)alloc((size_t)2048 * 32 * 4);
  float* rcos  = (float*)alloc((size_t)2048 * 32 * 4);
  u16* xb      = (u16*)alloc((size_t)8192 * 1024 * 2);
  u16* Wqkvt   = (u16*)alloc((size_t)3072 * 1024 * 2);
  u16* Wprojt  = (u16*)alloc((size_t)1024 * 1024 * 2);
  u16* Qg      = (u16*)alloc((size_t)64 * 2048 * 64 * 2);
  u16* Kg      = (u16*)alloc((size_t)64 * 2048 * 64 * 2);
  u16* Vtg     = (u16*)alloc((size_t)64 * 2048 * 64 * 2);
  u16* AOg     = (u16*)alloc((size_t)8192 * 1024 * 2);

  rope_table_kernel<<<256, 256, 0, stream>>>(rsin, rcos);
  cvt_bf16_kernel<<<4096, 256, 0, stream>>>(x, xb);
  transpose_cvt_kernel<<<dim3(96, 32), 256, 0, stream>>>(Wqkv, Wqkvt, 1024, 3072);
  transpose_cvt_kernel<<<dim3(32, 32), 256, 0, stream>>>(Wproj, Wprojt, 1024, 1024);
  gemm_kernel<0><<<dim3(64, 24), 256, 0, stream>>>(xb, Wqkvt, bqkv, rsin, rcos,
                                                   Qg, Kg, Vtg, nullptr, 1024);
  attn_kernel<<<512, 512, 0, stream>>>(Qg, Kg, Vtg, AOg);
  gemm_kernel<1><<<dim3(64, 8), 256, 0, stream>>>(AOg, Wprojt, bproj, nullptr, nullptr,
                                                  nullptr, nullptr, nullptr, out, 1024);
}

// Round 5
// 220.253 us; speedup vs baseline: 1.7545x; 1.0146x over previous
//
#include <hip/hip_runtime.h>
#include <stdint.h>

// ---------------------------------------------------------------------------
// SelfAttentionRope fused pipeline (round 5)
//   B=4 T=2048 D=1024 H=16 DH=64   M = B*T = 8192
//   R4 failure root-caused: xhalf_* permlane helpers could alias both asm
//   operands to one VGPR (same CSE'd value) -> in-place swap, broken reduce.
//   Fix: cross-half reductions via proven __shfl_xor(...,32). Keep the rest:
//   256-thr attn blocks (VGPR-resident acc), fexp2 asm, XCD swizzle on GEMMs.
// ---------------------------------------------------------------------------

typedef float  f32x4  __attribute__((ext_vector_type(4)));
typedef float  f32x16 __attribute__((ext_vector_type(16)));
typedef short  s16x8  __attribute__((ext_vector_type(8)));
typedef unsigned int u32x4 __attribute__((ext_vector_type(4)));
typedef unsigned short u16;
typedef unsigned int   u32;

#define LOG2E 1.4426950408889634f

__device__ __forceinline__ u16 f2bf(float f) {
  u32 u = __float_as_uint(f);
  u32 r = (u + 0x7fffu + ((u >> 16) & 1u)) >> 16;   // RNE
  return (u16)r;
}

__device__ __forceinline__ u32 cvtpk_bf16(float lo, float hi) {
  u32 w;
  asm("v_cvt_pk_bf16_f32 %0, %1, %2" : "=v"(w) : "v"(lo), "v"(hi));
  return w;
}

// raw transcendental exp2 (pure asm: schedulable, CSE-able)
__device__ __forceinline__ float fexp2(float x) {
  float r;
  asm("v_exp_f32 %0, %1" : "=v"(r) : "v"(x));
  return r;
}

// async global -> LDS, 16 B per lane (dest = wave-uniform base + lane*16)
__device__ __forceinline__ void gload_lds16(const u16* g, u16* l) {
  __builtin_amdgcn_global_load_lds(
      (const __attribute__((address_space(1))) uint32_t*)g,
      (__attribute__((address_space(3))) uint32_t*)l, 16, 0, 0);
}

__device__ __forceinline__ float vmax16(f32x16 v) {
  float a = fmaxf(fmaxf(v[0], v[1]), v[2]);
  float b = fmaxf(fmaxf(v[3], v[4]), v[5]);
  float c = fmaxf(fmaxf(v[6], v[7]), v[8]);
  float d = fmaxf(fmaxf(v[9], v[10]), v[11]);
  float e = fmaxf(fmaxf(v[12], v[13]), v[14]);
  float x = fmaxf(fmaxf(a, b), c);
  float y = fmaxf(fmaxf(d, e), v[15]);
  return fmaxf(x, y);
}

// ---- 0) rope table -------------------------------------------------------
__global__ void rope_table_kernel(float* __restrict__ rsin, float* __restrict__ rcos) {
  int idx = blockIdx.x * 256 + threadIdx.x;   // 2048*32 = 65536
  int t = idx >> 5, i = idx & 31;
  float invf = 1.0f / powf(10000.0f, (float)i * (1.0f / 32.0f));
  float ang = (float)t * invf;
  rsin[idx] = sinf(ang);
  rcos[idx] = cosf(ang);
}

// ---- 1) f32 -> bf16 (8 elems/thread) -------------------------------------
__global__ void cvt_bf16_kernel(const float* __restrict__ in, u16* __restrict__ out) {
  int i = blockIdx.x * 256 + threadIdx.x;
  const float4* p = reinterpret_cast<const float4*>(in) + (size_t)i * 2;
  float4 a = p[0], b = p[1];
  u32 w0 = (u32)f2bf(a.x) | ((u32)f2bf(a.y) << 16);
  u32 w1 = (u32)f2bf(a.z) | ((u32)f2bf(a.w) << 16);
  u32 w2 = (u32)f2bf(b.x) | ((u32)f2bf(b.y) << 16);
  u32 w3 = (u32)f2bf(b.z) | ((u32)f2bf(b.w) << 16);
  reinterpret_cast<uint4*>(out)[i] = make_uint4(w0, w1, w2, w3);
}

// ---- 2) W [K][N] f32 -> Wt [N][K] bf16 -----------------------------------
__global__ void transpose_cvt_kernel(const float* __restrict__ W, u16* __restrict__ Wt,
                                     int rows /*K*/, int cols /*N*/) {
  __shared__ float tile[32][33];
  int k0 = blockIdx.y * 32, n0 = blockIdx.x * 32;
  int t = threadIdx.x;
  int c = t & 31, r0 = t >> 5;
  #pragma unroll
  for (int i = 0; i < 4; i++) {
    int r = r0 + i * 8;
    tile[r][c] = W[(size_t)(k0 + r) * cols + n0 + c];
  }
  __syncthreads();
  int kk = t & 31, nn0 = t >> 5;
  #pragma unroll
  for (int i = 0; i < 4; i++) {
    int nn = nn0 + i * 8;
    Wt[(size_t)(n0 + nn) * rows + k0 + kk] = f2bf(tile[kk][nn]);
  }
}

// ---- 3/5) GEMM: A[M][K]bf16 @ Bt[N][K]bf16 ; 128x128 tile, BK=64 ---------
// LDS [128][64] u16, XOR-swizzled at 16B granularity; global_load_lds(16B)
// from pre-swizzled global source. XCD-chunked block swizzle (gridX must be 64).
template<int MODE>
__global__ __launch_bounds__(256) void gemm_kernel(
    const u16* __restrict__ A, const u16* __restrict__ Bt,
    const float* __restrict__ bias,
    const float* __restrict__ rsin, const float* __restrict__ rcos,
    u16* __restrict__ Qg, u16* __restrict__ Kg, u16* __restrict__ Vtg,
    float* __restrict__ Cout, int K)
{
  __shared__ alignas(16) u16 As[128][64];
  __shared__ alignas(16) u16 Bs[128][64];
  int tid = threadIdx.x;
  int lane = tid & 63, wid = tid >> 6;
  int wr = wid >> 1, wc = wid & 1;
  int l15 = lane & 15, lg = lane >> 4;

  // T1: bijective XCD-chunked swizzle (nwg = 64*gridY, divisible by 8)
  int nwg  = (int)(gridDim.x * gridDim.y);
  int orig = (int)(blockIdx.y * gridDim.x + blockIdx.x);
  int swz  = (orig & 7) * (nwg >> 3) + (orig >> 3);
  int row0 = (swz & 63) * 128, col0 = (swz >> 6) * 128;

  f32x4 acc[4][4] = {};

  // staging geometry: issue i stages rows wid*32 + i*8 + (lane>>3)
  int sr = lane >> 3, sc = lane & 7;
  int scol = (sc ^ sr) * 8;                       // pre-swizzled source col
  const u16* asrc = A  + (size_t)(row0 + wid * 32 + sr) * K + scol;
  const u16* bsrc = Bt + (size_t)(col0 + wid * 32 + sr) * K + scol;
  u16* aLds = &As[0][0] + wid * 2048;
  u16* bLds = &Bs[0][0] + wid * 2048;

  for (int k0 = 0; k0 < K; k0 += 64) {
    #pragma unroll
    for (int i = 0; i < 4; i++) {
      gload_lds16(asrc + (size_t)(i * 8) * K + k0, aLds + i * 512);
      gload_lds16(bsrc + (size_t)(i * 8) * K + k0, bLds + i * 512);
    }
    __syncthreads();   // drains vmcnt: tiles resident
    #pragma unroll
    for (int kk = 0; kk < 2; kk++) {
      s16x8 af[4], bf[4];
      #pragma unroll
      for (int m = 0; m < 4; m++) {
        int row = wr * 64 + m * 16 + l15;
        int slot = (kk * 4 + lg) ^ (l15 & 7);
        af[m] = *reinterpret_cast<const s16x8*>(&As[row][slot * 8]);
      }
      #pragma unroll
      for (int n = 0; n < 4; n++) {
        int row = wc * 64 + n * 16 + l15;
        int slot = (kk * 4 + lg) ^ (l15 & 7);
        bf[n] = *reinterpret_cast<const s16x8*>(&Bs[row][slot * 8]);
      }
      #pragma unroll
      for (int m = 0; m < 4; m++)
        #pragma unroll
        for (int n = 0; n < 4; n++)
          acc[m][n] = __builtin_amdgcn_mfma_f32_16x16x32_bf16(af[m], bf[n], acc[m][n], 0, 0, 0);
    }
    __syncthreads();   // all reads done before next stage overwrites
  }

  if (MODE == 0) {
    int wavecol = col0 + wc * 64;
    int sec = wavecol >> 10;
    int h = (wavecol & 1023) >> 6;
    #pragma unroll
    for (int m = 0; m < 4; m++) {
      int rbase = row0 + wr * 64 + m * 16 + lg * 4;
      if (sec < 2) {
        u16* G = (sec == 0) ? Qg : Kg;
        // Q gets 1/sqrt(dh) AND log2(e) folded in (softmax in log2 domain)
        float qs = (sec == 0) ? 0.125f * LOG2E : 1.0f;
        #pragma unroll
        for (int fc = 0; fc < 2; fc++) {
          int dh = fc * 16 + l15;
          float b1 = bias[wavecol + fc * 16 + l15];
          float b2 = bias[wavecol + fc * 16 + l15 + 32];
          #pragma unroll
          for (int j = 0; j < 4; j++) {
            int grow = rbase + j;
            int bidx = grow >> 11, tt = grow & 2047;
            float sn = rsin[tt * 32 + dh], cs = rcos[tt * 32 + dh];
            float v1 = acc[m][fc][j] + b1;
            float v2 = acc[m][fc + 2][j] + b2;
            float lo = (v1 * cs - v2 * sn) * qs;
            float hi = (v1 * sn + v2 * cs) * qs;
            size_t base = ((size_t)(bidx * 16 + h) * 2048 + tt) * 64;
            G[base + dh]      = f2bf(lo);
            G[base + dh + 32] = f2bf(hi);
          }
        }
      } else {
        #pragma unroll
        for (int fc = 0; fc < 4; fc++) {
          int dh = fc * 16 + l15;
          float bb = bias[wavecol + fc * 16 + l15];
          #pragma unroll
          for (int j = 0; j < 4; j++) {
            int grow = rbase + j;
            int bidx = grow >> 11, tt = grow & 2047;
            Vtg[((size_t)(bidx * 16 + h) * 64 + dh) * 2048 + tt] = f2bf(acc[m][fc][j] + bb);
          }
        }
      }
    }
  } else {
    #pragma unroll
    for (int m = 0; m < 4; m++) {
      int grow = row0 + wr * 64 + m * 16 + lg * 4;
      #pragma unroll
      for (int fc = 0; fc < 4; fc++) {
        int col = col0 + wc * 64 + fc * 16 + l15;
        float bb = bias[col];
        #pragma unroll
        for (int j = 0; j < 4; j++)
          Cout[(size_t)(grow + j) * 1024 + col] = acc[m][fc][j] + bb;
      }
    }
  }
}

// ---- 4) flash attention: 4-wave blocks, 32x32 MFMA, in-reg log2 softmax --
// grid bx = qt*64 + bh (qt 0..15): same-bh blocks land on one XCD.
// Per wave: 32 q-rows. KV tile 64, static dbuf, gload_lds staging.
__global__ __launch_bounds__(256, 3) void attn_kernel(
    const u16* __restrict__ Qg, const u16* __restrict__ Kg, const u16* __restrict__ Vtg,
    u16* __restrict__ Og)
{
  __shared__ alignas(16) u16 Ks[2][4096];   // [key][dh] swizzled (16B chunks)
  __shared__ alignas(16) u16 Vs[2][4096];   // [d][key]  swizzled
  int tid = threadIdx.x;
  int lane = tid & 63, wid = tid >> 6;      // wid 0..3
  int l31 = lane & 31, hi = lane >> 5;
  int bh = blockIdx.x & 63, qt = blockIdx.x >> 6;
  int q = qt * 128 + wid * 32 + l31;
  size_t bh2048 = (size_t)bh * 2048;

  // Q B-frags (Q pre-scaled by 0.125*log2e)
  s16x8 aq[4];
  #pragma unroll
  for (int kc = 0; kc < 4; kc++)
    aq[kc] = *reinterpret_cast<const s16x8*>(Qg + (bh2048 + q) * 64 + kc * 16 + hi * 8);

  f32x16 o0 = {}, o1 = {};
  float m_run = -3.0e38f, l_run = 0.f;

  // staging: wave stages 16 rows of K and of V per tile (2 gloads each)
  int sr = lane >> 3, sc = lane & 7;
  int scol = (sc ^ sr) * 8;                 // pre-swizzled source col
  const u16* kg0 = Kg  + (bh2048 + wid * 16 + sr) * 64 + scol;
  const u16* kg1 = kg0 + 8 * 64;
  const u16* vg0 = Vtg + ((size_t)bh * 64 + wid * 16 + sr) * 2048 + scol;
  const u16* vg1 = vg0 + 8 * 2048;
  int sdst = wid * 1024;

  // loop-invariant LDS read offsets (u16): row (c*32+l31), chunk (j*2+hi)^(l31&7)
  int offs[2][4];
  #pragma unroll
  for (int c = 0; c < 2; c++)
    #pragma unroll
    for (int j = 0; j < 4; j++)
      offs[c][j] = (c * 32 + l31) * 64 + (((j * 2 + hi) ^ (l31 & 7)) * 8);

#define STAGE(TT, BUF) do { \
    gload_lds16(kg0 + (size_t)(TT) * 4096, &Ks[BUF][sdst]); \
    gload_lds16(kg1 + (size_t)(TT) * 4096, &Ks[BUF][sdst + 512]); \
    gload_lds16(vg0 + (size_t)(TT) * 64,   &Vs[BUF][sdst]); \
    gload_lds16(vg1 + (size_t)(TT) * 64,   &Vs[BUF][sdst + 512]); \
  } while (0)

#define COMPUTE(B) do { \
    const u16* kb = &Ks[B][0]; \
    const u16* vb = &Vs[B][0]; \
    f32x16 s0 = {}, s1 = {}; \
    __builtin_amdgcn_s_setprio(1); \
    _Pragma("unroll") \
    for (int j = 0; j < 4; j++) { \
      s16x8 kf0 = *reinterpret_cast<const s16x8*>(kb + offs[0][j]); \
      s16x8 kf1 = *reinterpret_cast<const s16x8*>(kb + offs[1][j]); \
      s0 = __builtin_amdgcn_mfma_f32_32x32x16_bf16(kf0, aq[j], s0, 0, 0, 0); \
      s1 = __builtin_amdgcn_mfma_f32_32x32x16_bf16(kf1, aq[j], s1, 0, 0, 0); \
    } \
    __builtin_amdgcn_s_setprio(0); \
    float pm = fmaxf(vmax16(s0), vmax16(s1)); \
    pm = fmaxf(pm, __shfl_xor(pm, 32)); \
    if (!__all(pm - m_run <= 11.5f)) {          /* defer-max, log2 units */ \
      float mnew = fmaxf(m_run, pm); \
      float al = fexp2(m_run - mnew); \
      m_run = mnew; l_run *= al; \
      _Pragma("unroll") \
      for (int i = 0; i < 16; i++) { o0[i] *= al; o1[i] *= al; } \
    } \
    _Pragma("unroll") \
    for (int i = 0; i < 16; i++) { \
      s0[i] = fexp2(s0[i] - m_run); \
      s1[i] = fexp2(s1[i] - m_run); \
    } \
    float r0 = 0.f, r1 = 0.f, r2 = 0.f, r3 = 0.f; \
    _Pragma("unroll") \
    for (int i = 0; i < 4; i++) { \
      r0 += s0[i] + s0[i + 8]; \
      r1 += s0[i + 4] + s0[i + 12]; \
      r2 += s1[i] + s1[i + 8]; \
      r3 += s1[i + 4] + s1[i + 12]; \
    } \
    float rs = (r0 + r1) + (r2 + r3); \
    rs += __shfl_xor(rs, 32); \
    l_run += rs; \
    s16x8 pf[4]; \
    _Pragma("unroll") \
    for (int ks = 0; ks < 2; ks++) { \
      int rr = ks * 8; \
      u32 a0 = cvtpk_bf16(s0[rr + 0], s0[rr + 1]); \
      u32 b0 = cvtpk_bf16(s0[rr + 4], s0[rr + 5]); \
      u32 a1 = cvtpk_bf16(s0[rr + 2], s0[rr + 3]); \
      u32 b1 = cvtpk_bf16(s0[rr + 6], s0[rr + 7]); \
      asm volatile("v_permlane32_swap_b32 %0, %1" : "+v"(a0), "+v"(b0)); \
      asm volatile("v_permlane32_swap_b32 %0, %1" : "+v"(a1), "+v"(b1)); \
      u32x4 w = {a0, a1, b0, b1}; \
      pf[ks] = __builtin_bit_cast(s16x8, w); \
    } \
    _Pragma("unroll") \
    for (int ks = 0; ks < 2; ks++) { \
      int rr = ks * 8; \
      u32 a0 = cvtpk_bf16(s1[rr + 0], s1[rr + 1]); \
      u32 b0 = cvtpk_bf16(s1[rr + 4], s1[rr + 5]); \
      u32 a1 = cvtpk_bf16(s1[rr + 2], s1[rr + 3]); \
      u32 b1 = cvtpk_bf16(s1[rr + 6], s1[rr + 7]); \
      asm volatile("v_permlane32_swap_b32 %0, %1" : "+v"(a0), "+v"(b0)); \
      asm volatile("v_permlane32_swap_b32 %0, %1" : "+v"(a1), "+v"(b1)); \
      u32x4 w = {a0, a1, b0, b1}; \
      pf[ks + 2] = __builtin_bit_cast(s16x8, w); \
    } \
    __builtin_amdgcn_s_setprio(1); \
    _Pragma("unroll") \
    for (int ks = 0; ks < 4; ks++) { \
      s16x8 vf = *reinterpret_cast<const s16x8*>(vb + offs[0][ks]); \
      o0 = __builtin_amdgcn_mfma_f32_32x32x16_bf16(vf, pf[ks], o0, 0, 0, 0); \
    } \
    _Pragma("unroll") \
    for (int ks = 0; ks < 4; ks++) { \
      s16x8 vf = *reinterpret_cast<const s16x8*>(vb + offs[1][ks]); \
      o1 = __builtin_amdgcn_mfma_f32_32x32x16_bf16(vf, pf[ks], o1, 0, 0, 0); \
    } \
    __builtin_amdgcn_s_setprio(0); \
  } while (0)

  STAGE(0, 0);
  __syncthreads();

  for (int it = 0; it < 16; it++) {
    STAGE(2 * it + 1, 1);
    COMPUTE(0);
    __syncthreads();          // drains stage->b1; b0 reads complete
    if (it < 15) STAGE(2 * it + 2, 0);
    COMPUTE(1);
    __syncthreads();          // drains stage->b0; b1 reads complete
  }
#undef STAGE
#undef COMPUTE

  // epilogue: normalize (lane-local) and store O^T -> Og[b][t][h*64+d]
  float inv = 1.0f / l_run;
  int b = bh >> 4, h = bh & 15;
  size_t rowbase = ((size_t)b * 2048 + q) * 1024 + h * 64;
  #pragma unroll
  for (int c2 = 0; c2 < 2; c2++) {
    #pragma unroll
    for (int g = 0; g < 4; g++) {
      float e0 = (c2 ? o1[g * 4 + 0] : o0[g * 4 + 0]) * inv;
      float e1 = (c2 ? o1[g * 4 + 1] : o0[g * 4 + 1]) * inv;
      float e2 = (c2 ? o1[g * 4 + 2] : o0[g * 4 + 2]) * inv;
      float e3 = (c2 ? o1[g * 4 + 3] : o0[g * 4 + 3]) * inv;
      u32 w0 = cvtpk_bf16(e0, e1);
      u32 w1 = cvtpk_bf16(e2, e3);
      int d = c2 * 32 + g * 8 + hi * 4;
      uint2 val; val.x = w0; val.y = w1;
      *reinterpret_cast<uint2*>(Og + rowbase + d) = val;
    }
  }
}

// ---------------------------------------------------------------------------
extern "C" void kernel_launch(void* const* d_in, const int* in_sizes, int n_in,
                              void* d_out, int out_size, void* d_ws, size_t ws_size,
                              hipStream_t stream) {
  const float* x     = (const float*)d_in[0];
  const float* Wqkv  = (const float*)d_in[1];
  const float* bqkv  = (const float*)d_in[2];
  const float* Wproj = (const float*)d_in[3];
  const float* bproj = (const float*)d_in[4];
  float* out = (float*)d_out;

  char* ws = (char*)d_ws;
  size_t off = 0;
  auto alloc = [&](size_t bytes) {
    void* p = ws + off;
    off += (bytes + 255) & ~(size_t)255;
    return p;
  };
  float* rsin  = (float*)alloc((size_t)2048 * 32 * 4);
  float* rcos  = (float*)alloc((size_t)2048 * 32 * 4);
  u16* xb      = (u16*)alloc((size_t)8192 * 1024 * 2);
  u16* Wqkvt   = (u16*)alloc((size_t)3072 * 1024 * 2);
  u16* Wprojt  = (u16*)alloc((size_t)1024 * 1024 * 2);
  u16* Qg      = (u16*)alloc((size_t)64 * 2048 * 64 * 2);
  u16* Kg      = (u16*)alloc((size_t)64 * 2048 * 64 * 2);
  u16* Vtg     = (u16*)alloc((size_t)64 * 2048 * 64 * 2);
  u16* AOg     = (u16*)alloc((size_t)8192 * 1024 * 2);

  rope_table_kernel<<<256, 256, 0, stream>>>(rsin, rcos);
  cvt_bf16_kernel<<<4096, 256, 0, stream>>>(x, xb);
  transpose_cvt_kernel<<<dim3(96, 32), 256, 0, stream>>>(Wqkv, Wqkvt, 1024, 3072);
  transpose_cvt_kernel<<<dim3(32, 32), 256, 0, stream>>>(Wproj, Wprojt, 1024, 1024);
  gemm_kernel<0><<<dim3(64, 24), 256, 0, stream>>>(xb, Wqkvt, bqkv, rsin, rcos,
                                                   Qg, Kg, Vtg, nullptr, 1024);
  attn_kernel<<<1024, 256, 0, stream>>>(Qg, Kg, Vtg, AOg);
  gemm_kernel<1><<<dim3(64, 8), 256, 0, stream>>>(AOg, Wprojt, bproj, nullptr, nullptr,
                                                  nullptr, nullptr, nullptr, out, 1024);
}